// Round 4
// baseline (11895.700 us; speedup 1.0000x reference)
//
#include <hip/hip_runtime.h>

#define TT 2048
#define BB 256
#define HID 64
#define NB 16   // batches per recurrence block

typedef _Float16 half8 __attribute__((ext_vector_type(8)));
typedef float f32x4 __attribute__((ext_vector_type(4)));

__device__ __forceinline__ float frcp(float x) { return __builtin_amdgcn_rcpf(x); }
__device__ __forceinline__ float fsig(float x) { return frcp(1.f + __expf(-x)); }
// tanh(x) = 1 - 2/(1+e^{2x}) : stable at +/-inf
__device__ __forceinline__ float ftanh(float x) { return 1.f - 2.f * frcp(1.f + __expf(2.f * x)); }

// async global->LDS DMA, 16B per lane. LDS dest is WAVE-UNIFORM base;
// HW places lane L's data at base + 16*L. Source is per-lane.
__device__ __forceinline__ void async_copy16(const void* g, void* l) {
    __builtin_amdgcn_global_load_lds(
        (const __attribute__((address_space(1))) void*)g,
        (__attribute__((address_space(3))) void*)l, 16, 0, 0);
}

// ---------------- fp32 input-projection GEMM ----------------
__global__ __launch_bounds__(256, 2) void gemm_pre_k(
    const float* __restrict__ in, const float* __restrict__ W,
    const float* __restrict__ b_ih, const float* __restrict__ b_hh,
    float* __restrict__ out, int K)
{
    __shared__ __align__(16) float in_s[64][20];
    __shared__ __align__(16) float w_s[16][256];

    const int tid = threadIdx.x;
    const int tx = tid & 15, ty = tid >> 4;
    const long long row0 = (long long)blockIdx.x * 64;

    float4 bias[4];
    {
        const float4* bi4 = (const float4*)b_ih;
        const float4* bh4 = (const float4*)b_hh;
#pragma unroll
        for (int jj = 0; jj < 4; ++jj) {
            float4 a = bi4[tx * 4 + jj], b = bh4[tx * 4 + jj];
            bias[jj] = make_float4(a.x + b.x, a.y + b.y, a.z + b.z, a.w + b.w);
        }
    }

    float4 acc[4][4];
#pragma unroll
    for (int i = 0; i < 4; ++i)
#pragma unroll
        for (int j = 0; j < 4; ++j) acc[i][j] = make_float4(0.f, 0.f, 0.f, 0.f);

    const int rs = tid >> 2;
    const int kq = tid & 3;

    for (int kc = 0; kc < K; kc += 16) {
        __syncthreads();
        float4 iv = *(const float4*)(in + (row0 + rs) * K + kc + kq * 4);
        *(float4*)(&in_s[rs][kq * 4]) = iv;
        const float* wr = W + (long long)tid * K + kc;
        float4 w0 = ((const float4*)wr)[0];
        float4 w1 = ((const float4*)wr)[1];
        float4 w2 = ((const float4*)wr)[2];
        float4 w3 = ((const float4*)wr)[3];
        w_s[0][tid] = w0.x;  w_s[1][tid] = w0.y;  w_s[2][tid] = w0.z;  w_s[3][tid] = w0.w;
        w_s[4][tid] = w1.x;  w_s[5][tid] = w1.y;  w_s[6][tid] = w1.z;  w_s[7][tid] = w1.w;
        w_s[8][tid] = w2.x;  w_s[9][tid] = w2.y;  w_s[10][tid] = w2.z; w_s[11][tid] = w2.w;
        w_s[12][tid] = w3.x; w_s[13][tid] = w3.y; w_s[14][tid] = w3.z; w_s[15][tid] = w3.w;
        __syncthreads();

#pragma unroll
        for (int k2 = 0; k2 < 4; ++k2) {
            float4 a[4];
#pragma unroll
            for (int i = 0; i < 4; ++i) a[i] = *(const float4*)(&in_s[ty * 4 + i][k2 * 4]);
#pragma unroll
            for (int kk = 0; kk < 4; ++kk) {
                const int k = k2 * 4 + kk;
                float4 wv[4];
#pragma unroll
                for (int jj = 0; jj < 4; ++jj) wv[jj] = *(const float4*)(&w_s[k][tx * 16 + jj * 4]);
#pragma unroll
                for (int i = 0; i < 4; ++i) {
                    const float av = ((const float*)&a[i])[kk];
#pragma unroll
                    for (int jj = 0; jj < 4; ++jj) {
                        acc[i][jj].x += av * wv[jj].x;
                        acc[i][jj].y += av * wv[jj].y;
                        acc[i][jj].z += av * wv[jj].z;
                        acc[i][jj].w += av * wv[jj].w;
                    }
                }
            }
        }
    }

#pragma unroll
    for (int i = 0; i < 4; ++i) {
        float4* op = (float4*)(out + (row0 + ty * 4 + i) * 256 + tx * 16);
#pragma unroll
        for (int jj = 0; jj < 4; ++jj) {
            float4 v = acc[i][jj];
            v.x += bias[jj].x; v.y += bias[jj].y; v.z += bias[jj].z; v.w += bias[jj].w;
            op[jj] = v;
        }
    }
}

// ---------------- MFMA recurrence with LDS-staged pre ----------------
// 16 blocks, 256 threads (4 waves). Block = batches [blk*16, blk*16+16).
// gates[256,16] = W_hh @ H + pre_t via mfma_f32_16x16x32_f16, 3-term split-f16.
// pre staged into LDS by async DMA (global_load_lds, per-lane permuted source)
// in a 3-slot ring, 2 steps ahead; slots are wave-private so the per-step
// __syncthreads vmcnt drain retires a 2-step-old DMA for free. No global
// loads on the per-step critical path.
__global__ __launch_bounds__(256) void lstm_rec_mfma(
    const float* __restrict__ pre, const float* __restrict__ w_hh,
    float* __restrict__ h_out, float* __restrict__ out,
    const float* __restrict__ fc_w, const float* __restrict__ fc_b,
    int mode)
{
    __shared__ __align__(16) float PRE[3][4][4][256]; // [slot][wave][m][lane*4] 48 KB
    __shared__ half8 HEX[2][16][16];   // h exchange: [buf][slot][n ^ (slot>>1)], hi|lo f16
    __shared__ float FCP[2][4][16];    // FC partials

    const int tid = threadIdx.x;
    const int w = tid >> 6, lane = tid & 63;
    const int n = lane & 15, quad = lane >> 4;
    const int blk = blockIdx.x;
    const long long b = (long long)blk * NB + n;

    // zero exchange buffer 0 (h_0 = 0)
    HEX[0][tid >> 4][tid & 15] = (half8){0, 0, 0, 0, 0, 0, 0, 0};

    // ---- preload W_hh fragments (A operands), split f16 hi/lo ----
    half8 Ahi[4][2], Alo[4][2];
#pragma unroll
    for (int m = 0; m < 4; ++m) {
        const int row = 16 * (w + 4 * m) + n;
#pragma unroll
        for (int kt = 0; kt < 2; ++kt) {
            const float* wp_ = w_hh + row * 64 + 32 * kt + 8 * quad;
            f32x4 a0 = *(const f32x4*)wp_;
            f32x4 a1 = *(const f32x4*)(wp_ + 4);
            half8 hi, lo;
#pragma unroll
            for (int j = 0; j < 4; ++j) {
                _Float16 h0 = (_Float16)a0[j];
                _Float16 h1 = (_Float16)a1[j];
                hi[j] = h0;     lo[j] = (_Float16)(a0[j] - (float)h0);
                hi[4 + j] = h1; lo[4 + j] = (_Float16)(a1[j] - (float)h1);
            }
            Ahi[m][kt] = hi; Alo[m][kt] = lo;
        }
    }

    // FC weights (mode 2)
    f32x4 fw = {0.f, 0.f, 0.f, 0.f};
    float fcbv = 0.f;
    if (mode == 2) {
        fw = *(const f32x4*)(fc_w + 16 * w + 4 * quad);
        fcbv = fc_b[0];
    }

    // per-lane DMA source base: batch (blk*16+n), column 4*quad (+ 16*(w+4m) per group)
    const float* gbase = pre + (b * TT) * 256 + 4 * quad;

    // prologue: stage steps 0 and 1 into slots 0,1 (wave w stages its own groups)
#pragma unroll
    for (int m = 0; m < 4; ++m) async_copy16(gbase + 16 * (w + 4 * m), &PRE[0][w][m][0]);
#pragma unroll
    for (int m = 0; m < 4; ++m) async_copy16(gbase + 256 + 16 * (w + 4 * m), &PRE[1][w][m][0]);

    float* hob = (mode != 2) ? (h_out + (b * TT) * 64 + 16 * w + 4 * quad) : nullptr;
    float* oob = (mode == 2) ? (out + (long long)(blk * NB) * TT) : nullptr;

    float cst[4] = {0.f, 0.f, 0.f, 0.f};

    __syncthreads();   // HEX zero visible + prologue DMA drained

    int st = 0;        // ring slot for step t
    for (int t = 0; t < TT; ++t) {
        const int p = t & 1;

        // ---- issue DMA for step t+2 into the slot being freed this step ----
        if (t + 2 < TT) {
            const float* gs = gbase + (long long)(t + 2) * 256;
            const int s2 = (st + 2 >= 3) ? st - 1 : st + 2;
#pragma unroll
            for (int m = 0; m < 4; ++m) async_copy16(gs + 16 * (w + 4 * m), &PRE[s2][w][m][0]);
        }

        // ---- B fragments from LDS: B[k = 32*kt + 8*quad + j][n] ----
        half8 Bhi[2], Blo[2];
#pragma unroll
        for (int kt = 0; kt < 2; ++kt) {
            const int s0 = (2 * kt + (quad >> 1)) * 4 + 2 * (quad & 1);
            const int col = n ^ (s0 >> 1);
            half8 c0 = HEX[p][s0][col];
            half8 c1 = HEX[p][s0 + 1][col];
            Bhi[kt] = __builtin_shufflevector(c0, c1, 0, 1, 2, 3, 8, 9, 10, 11);
            Blo[kt] = __builtin_shufflevector(c0, c1, 4, 5, 6, 7, 12, 13, 14, 15);
        }

        // ---- gates = pre(LDS) + W@H (3-term split) ----
        f32x4 G[4];
#pragma unroll
        for (int m = 0; m < 4; ++m) {
            f32x4 C = *(const f32x4*)&PRE[st][w][m][lane * 4];   // conflict-free b128
#pragma unroll
            for (int kt = 0; kt < 2; ++kt) {
                C = __builtin_amdgcn_mfma_f32_16x16x32_f16(Ahi[m][kt], Bhi[kt], C, 0, 0, 0);
                C = __builtin_amdgcn_mfma_f32_16x16x32_f16(Ahi[m][kt], Blo[kt], C, 0, 0, 0);
                C = __builtin_amdgcn_mfma_f32_16x16x32_f16(Alo[m][kt], Bhi[kt], C, 0, 0, 0);
            }
            G[m] = C;
        }

        // ---- pointwise (in-wave: G[0]=i, G[1]=f, G[2]=g, G[3]=o) ----
        float hv[4];
#pragma unroll
        for (int r = 0; r < 4; ++r) {
            float iv = fsig(G[0][r]);
            float fv = fsig(G[1][r]);
            float gv = ftanh(G[2][r]);
            float ov = fsig(G[3][r]);
            cst[r] = fv * cst[r] + iv * gv;
            hv[r] = ov * ftanh(cst[r]);
        }

        // ---- write h exchange (next buffer), packed hi|lo ----
        {
            half8 pk;
#pragma unroll
            for (int r = 0; r < 4; ++r) {
                _Float16 hh = (_Float16)hv[r];
                pk[r] = hh;
                pk[4 + r] = (_Float16)(hv[r] - (float)hh);
            }
            const int s = w * 4 + quad;
            HEX[p ^ 1][s][n ^ (s >> 1)] = pk;
        }

        if (mode == 2) {
            float s = fw[0] * hv[0] + fw[1] * hv[1] + fw[2] * hv[2] + fw[3] * hv[3];
            s += __shfl_down(s, 32);
            s += __shfl_down(s, 16);
            if (quad == 0) FCP[p][w][n] = s;
        }

        __syncthreads();

        // ---- global stores AFTER the barrier: a full step old at next drain ----
        if (mode != 2) {
            f32x4 ho = {hv[0], hv[1], hv[2], hv[3]};
            *(f32x4*)hob = ho;
            hob += 64;
        } else if (w == 0 && lane < 16) {
            oob[(long long)lane * TT + t] =
                fcbv + FCP[p][0][lane] + FCP[p][1][lane] + FCP[p][2][lane] + FCP[p][3][lane];
        }

        st = (st + 1 >= 3) ? 0 : st + 1;
    }
}

extern "C" void kernel_launch(void* const* d_in, const int* in_sizes, int n_in,
                              void* d_out, int out_size, void* d_ws, size_t ws_size,
                              hipStream_t stream)
{
    const float* x    = (const float*)d_in[0];
    const float* wih0 = (const float*)d_in[1];
    const float* whh0 = (const float*)d_in[2];
    const float* bih0 = (const float*)d_in[3];
    const float* bhh0 = (const float*)d_in[4];
    const float* wih1 = (const float*)d_in[5];
    const float* whh1 = (const float*)d_in[6];
    const float* bih1 = (const float*)d_in[7];
    const float* bhh1 = (const float*)d_in[8];
    const float* wih2 = (const float*)d_in[9];
    const float* whh2 = (const float*)d_in[10];
    const float* bih2 = (const float*)d_in[11];
    const float* bhh2 = (const float*)d_in[12];
    const float* fcw  = (const float*)d_in[13];
    const float* fcb  = (const float*)d_in[14];
    float* outp = (float*)d_out;

    const long long R = (long long)BB * TT;      // 524288 rows
    float* pre  = (float*)d_ws;                  // R*256 fp32 = 512 MB
    float* hbuf = pre + R * 256;                 // R*64  fp32 = 128 MB

    const int gemm_grid = (int)(R / 64);         // 8192
    const int rec_grid = BB / NB;                // 16

    // layer 0
    gemm_pre_k<<<gemm_grid, 256, 0, stream>>>(x, wih0, bih0, bhh0, pre, 128);
    lstm_rec_mfma<<<rec_grid, 256, 0, stream>>>(pre, whh0, hbuf, nullptr, nullptr, nullptr, 0);
    // layer 1
    gemm_pre_k<<<gemm_grid, 256, 0, stream>>>(hbuf, wih1, bih1, bhh1, pre, 64);
    lstm_rec_mfma<<<rec_grid, 256, 0, stream>>>(pre, whh1, hbuf, nullptr, nullptr, nullptr, 1);
    // layer 2 with fused FC
    gemm_pre_k<<<gemm_grid, 256, 0, stream>>>(hbuf, wih2, bih2, bhh2, pre, 64);
    lstm_rec_mfma<<<rec_grid, 256, 0, stream>>>(pre, whh2, nullptr, outp, fcw, fcb, 2);
}

// Round 5
// 7094.394 us; speedup vs baseline: 1.6768x; 1.6768x over previous
//
#include <hip/hip_runtime.h>

#define TT 2048
#define BB 256
#define HID 64
#define NB 16   // batches per recurrence block

typedef _Float16 half8 __attribute__((ext_vector_type(8)));
typedef float f32x4 __attribute__((ext_vector_type(4)));

__device__ __forceinline__ float frcp(float x) { return __builtin_amdgcn_rcpf(x); }
__device__ __forceinline__ float fsig(float x) { return frcp(1.f + __expf(-x)); }
// tanh(x) = 1 - 2/(1+e^{2x}) : stable at +/-inf
__device__ __forceinline__ float ftanh(float x) { return 1.f - 2.f * frcp(1.f + __expf(2.f * x)); }

// ---------------- fp32 input-projection GEMM ----------------
__global__ __launch_bounds__(256, 2) void gemm_pre_k(
    const float* __restrict__ in, const float* __restrict__ W,
    const float* __restrict__ b_ih, const float* __restrict__ b_hh,
    float* __restrict__ out, int K)
{
    __shared__ __align__(16) float in_s[64][20];
    __shared__ __align__(16) float w_s[16][256];

    const int tid = threadIdx.x;
    const int tx = tid & 15, ty = tid >> 4;
    const long long row0 = (long long)blockIdx.x * 64;

    float4 bias[4];
    {
        const float4* bi4 = (const float4*)b_ih;
        const float4* bh4 = (const float4*)b_hh;
#pragma unroll
        for (int jj = 0; jj < 4; ++jj) {
            float4 a = bi4[tx * 4 + jj], b = bh4[tx * 4 + jj];
            bias[jj] = make_float4(a.x + b.x, a.y + b.y, a.z + b.z, a.w + b.w);
        }
    }

    float4 acc[4][4];
#pragma unroll
    for (int i = 0; i < 4; ++i)
#pragma unroll
        for (int j = 0; j < 4; ++j) acc[i][j] = make_float4(0.f, 0.f, 0.f, 0.f);

    const int rs = tid >> 2;
    const int kq = tid & 3;

    for (int kc = 0; kc < K; kc += 16) {
        __syncthreads();
        float4 iv = *(const float4*)(in + (row0 + rs) * K + kc + kq * 4);
        *(float4*)(&in_s[rs][kq * 4]) = iv;
        const float* wr = W + (long long)tid * K + kc;
        float4 w0 = ((const float4*)wr)[0];
        float4 w1 = ((const float4*)wr)[1];
        float4 w2 = ((const float4*)wr)[2];
        float4 w3 = ((const float4*)wr)[3];
        w_s[0][tid] = w0.x;  w_s[1][tid] = w0.y;  w_s[2][tid] = w0.z;  w_s[3][tid] = w0.w;
        w_s[4][tid] = w1.x;  w_s[5][tid] = w1.y;  w_s[6][tid] = w1.z;  w_s[7][tid] = w1.w;
        w_s[8][tid] = w2.x;  w_s[9][tid] = w2.y;  w_s[10][tid] = w2.z; w_s[11][tid] = w2.w;
        w_s[12][tid] = w3.x; w_s[13][tid] = w3.y; w_s[14][tid] = w3.z; w_s[15][tid] = w3.w;
        __syncthreads();

#pragma unroll
        for (int k2 = 0; k2 < 4; ++k2) {
            float4 a[4];
#pragma unroll
            for (int i = 0; i < 4; ++i) a[i] = *(const float4*)(&in_s[ty * 4 + i][k2 * 4]);
#pragma unroll
            for (int kk = 0; kk < 4; ++kk) {
                const int k = k2 * 4 + kk;
                float4 wv[4];
#pragma unroll
                for (int jj = 0; jj < 4; ++jj) wv[jj] = *(const float4*)(&w_s[k][tx * 16 + jj * 4]);
#pragma unroll
                for (int i = 0; i < 4; ++i) {
                    const float av = ((const float*)&a[i])[kk];
#pragma unroll
                    for (int jj = 0; jj < 4; ++jj) {
                        acc[i][jj].x += av * wv[jj].x;
                        acc[i][jj].y += av * wv[jj].y;
                        acc[i][jj].z += av * wv[jj].z;
                        acc[i][jj].w += av * wv[jj].w;
                    }
                }
            }
        }
    }

#pragma unroll
    for (int i = 0; i < 4; ++i) {
        float4* op = (float4*)(out + (row0 + ty * 4 + i) * 256 + tx * 16);
#pragma unroll
        for (int jj = 0; jj < 4; ++jj) {
            float4 v = acc[i][jj];
            v.x += bias[jj].x; v.y += bias[jj].y; v.z += bias[jj].z; v.w += bias[jj].w;
            op[jj] = v;
        }
    }
}

// ---------------- MFMA recurrence ----------------
// 16 blocks, 256 threads (4 waves). Block = batches [blk*16, blk*16+16).
// gates[256,16] = W_hh @ H + pre_t via mfma_f32_16x16x32_f16, 3-term split-f16.
// __syncthreads drains ALL vm ops (R3/R4 lesson) -> schedule global ops so
// they complete naturally before the barrier: pre[t+1] load issued at TOP of
// step t (full-step slack); h(t)/out(t) stores issued at TOP of step t+1.
// Loop unrolled x2 with explicit register sets (no dynamic indexing).
__global__ __launch_bounds__(256) void lstm_rec_mfma(
    const float* __restrict__ pre, const float* __restrict__ w_hh,
    float* __restrict__ h_out, float* __restrict__ out,
    const float* __restrict__ fc_w, const float* __restrict__ fc_b,
    int mode)
{
    __shared__ half8 HEX[2][16][16];   // h exchange: [buf][slot][n ^ (slot>>1)], hi|lo f16
    __shared__ float FCP[2][4][16];    // FC partials

    const int tid = threadIdx.x;
    const int w = tid >> 6, lane = tid & 63;
    const int n = lane & 15, quad = lane >> 4;
    const int blk = blockIdx.x;
    const long long b = (long long)blk * NB + n;

    // zero exchange buffer 0 (h_0 = 0)
    HEX[0][tid >> 4][tid & 15] = (half8){0, 0, 0, 0, 0, 0, 0, 0};

    // ---- preload W_hh fragments (A operands), split f16 hi/lo ----
    // A[m = lane&15][k = 32*kt + 8*quad + j]
    half8 Ahi[4][2], Alo[4][2];
#pragma unroll
    for (int m = 0; m < 4; ++m) {
        const int row = 16 * (w + 4 * m) + n;
#pragma unroll
        for (int kt = 0; kt < 2; ++kt) {
            const float* wp_ = w_hh + row * 64 + 32 * kt + 8 * quad;
            f32x4 a0 = *(const f32x4*)wp_;
            f32x4 a1 = *(const f32x4*)(wp_ + 4);
            half8 hi, lo;
#pragma unroll
            for (int j = 0; j < 4; ++j) {
                _Float16 h0 = (_Float16)a0[j];
                _Float16 h1 = (_Float16)a1[j];
                hi[j] = h0;     lo[j] = (_Float16)(a0[j] - (float)h0);
                hi[4 + j] = h1; lo[4 + j] = (_Float16)(a1[j] - (float)h1);
            }
            Ahi[m][kt] = hi; Alo[m][kt] = lo;
        }
    }

    // FC weights (mode 2)
    f32x4 fw = {0.f, 0.f, 0.f, 0.f};
    float fcbv = 0.f;
    if (mode == 2) {
        fw = *(const f32x4*)(fc_w + 16 * w + 4 * quad);
        fcbv = fc_b[0];
    }

    // per-thread pre base: batch b, column 16*w + 4*quad (+ m*64 per group)
    const float* pbase = pre + (b * TT) * 256 + 16 * w + 4 * quad;

    float* hob = (mode != 2) ? (h_out + (b * TT) * 64 + 16 * w + 4 * quad) : nullptr;
    float* oob = (mode == 2) ? (out + (long long)(blk * NB) * TT) : nullptr;

    float cst[4] = {0.f, 0.f, 0.f, 0.f};
    f32x4 hprev = {0.f, 0.f, 0.f, 0.f};   // h from previous step, stored one step late
    float fc_prev = 0.f;                   // not used; FCP carries mode-2 partials

    // P for step 0
    f32x4 Pa[4], Pb[4];
#pragma unroll
    for (int m = 0; m < 4; ++m) Pa[m] = *(const f32x4*)(pbase + m * 64);

    __syncthreads();   // HEX zero visible

    // one LSTM step; PAR = t&1 (compile-time at each call site)
    auto do_step = [&](int t, int PAR, f32x4* Pcur, f32x4* Pnxt) __attribute__((always_inline)) {
        // ---- deferred global stores from step t-1 (full-step slack to drain) ----
        if (t > 0) {
            if (mode != 2) {
                *(f32x4*)(hob + (long long)(t - 1) * 64) = hprev;
            } else if (w == 0 && lane < 16) {
                const int pp = PAR ^ 1;
                oob[(long long)lane * TT + (t - 1)] =
                    fcbv + FCP[pp][0][lane] + FCP[pp][1][lane] + FCP[pp][2][lane] + FCP[pp][3][lane];
            }
        }

        // ---- issue pre[t+1] prefetch NOW (completes before this step's barrier) ----
        {
            const int tn = (t + 1 < TT) ? t + 1 : t;
            const float* pf = pbase + (long long)tn * 256;
#pragma unroll
            for (int m = 0; m < 4; ++m) Pnxt[m] = *(const f32x4*)(pf + m * 64);
        }

        // ---- B fragments from LDS: B[k = 32*kt + 8*quad + j][n] ----
        half8 Bhi[2], Blo[2];
#pragma unroll
        for (int kt = 0; kt < 2; ++kt) {
            const int s0 = (2 * kt + (quad >> 1)) * 4 + 2 * (quad & 1);
            const int col = n ^ (s0 >> 1);
            half8 c0 = HEX[PAR][s0][col];
            half8 c1 = HEX[PAR][s0 + 1][col];
            Bhi[kt] = __builtin_shufflevector(c0, c1, 0, 1, 2, 3, 8, 9, 10, 11);
            Blo[kt] = __builtin_shufflevector(c0, c1, 4, 5, 6, 7, 12, 13, 14, 15);
        }

        // ---- gates = pre + W@H (3-term split) ----
        f32x4 G[4];
#pragma unroll
        for (int m = 0; m < 4; ++m) {
            f32x4 C = Pcur[m];
#pragma unroll
            for (int kt = 0; kt < 2; ++kt) {
                C = __builtin_amdgcn_mfma_f32_16x16x32_f16(Ahi[m][kt], Bhi[kt], C, 0, 0, 0);
                C = __builtin_amdgcn_mfma_f32_16x16x32_f16(Ahi[m][kt], Blo[kt], C, 0, 0, 0);
                C = __builtin_amdgcn_mfma_f32_16x16x32_f16(Alo[m][kt], Bhi[kt], C, 0, 0, 0);
            }
            G[m] = C;
        }

        // ---- pointwise (in-wave: G[0]=i, G[1]=f, G[2]=g, G[3]=o) ----
        float hv[4];
#pragma unroll
        for (int r = 0; r < 4; ++r) {
            float iv = fsig(G[0][r]);
            float fv = fsig(G[1][r]);
            float gv = ftanh(G[2][r]);
            float ov = fsig(G[3][r]);
            cst[r] = fv * cst[r] + iv * gv;
            hv[r] = ov * ftanh(cst[r]);
        }

        // ---- write h exchange (next buffer), packed hi|lo ----
        {
            half8 pk;
#pragma unroll
            for (int r = 0; r < 4; ++r) {
                _Float16 hh = (_Float16)hv[r];
                pk[r] = hh;
                pk[4 + r] = (_Float16)(hv[r] - (float)hh);
            }
            const int s = w * 4 + quad;
            HEX[PAR ^ 1][s][n ^ (s >> 1)] = pk;
        }

        if (mode == 2) {
            float s = fw[0] * hv[0] + fw[1] * hv[1] + fw[2] * hv[2] + fw[3] * hv[3];
            s += __shfl_down(s, 32);
            s += __shfl_down(s, 16);
            if (quad == 0) FCP[PAR][w][n] = s;
        } else {
            hprev = (f32x4){hv[0], hv[1], hv[2], hv[3]};
        }

        __syncthreads();
    };

    for (int t = 0; t < TT; t += 2) {
        do_step(t, 0, Pa, Pb);
        do_step(t + 1, 1, Pb, Pa);
    }

    // epilogue: store final step's outputs (t = TT-1, parity 1)
    if (mode != 2) {
        *(f32x4*)(hob + (long long)(TT - 1) * 64) = hprev;
    } else if (w == 0 && lane < 16) {
        oob[(long long)lane * TT + (TT - 1)] =
            fcbv + FCP[1][0][lane] + FCP[1][1][lane] + FCP[1][2][lane] + FCP[1][3][lane];
    }
    (void)fc_prev;
}

extern "C" void kernel_launch(void* const* d_in, const int* in_sizes, int n_in,
                              void* d_out, int out_size, void* d_ws, size_t ws_size,
                              hipStream_t stream)
{
    const float* x    = (const float*)d_in[0];
    const float* wih0 = (const float*)d_in[1];
    const float* whh0 = (const float*)d_in[2];
    const float* bih0 = (const float*)d_in[3];
    const float* bhh0 = (const float*)d_in[4];
    const float* wih1 = (const float*)d_in[5];
    const float* whh1 = (const float*)d_in[6];
    const float* bih1 = (const float*)d_in[7];
    const float* bhh1 = (const float*)d_in[8];
    const float* wih2 = (const float*)d_in[9];
    const float* whh2 = (const float*)d_in[10];
    const float* bih2 = (const float*)d_in[11];
    const float* bhh2 = (const float*)d_in[12];
    const float* fcw  = (const float*)d_in[13];
    const float* fcb  = (const float*)d_in[14];
    float* outp = (float*)d_out;

    const long long R = (long long)BB * TT;      // 524288 rows
    float* pre  = (float*)d_ws;                  // R*256 fp32 = 512 MB
    float* hbuf = pre + R * 256;                 // R*64  fp32 = 128 MB

    const int gemm_grid = (int)(R / 64);         // 8192
    const int rec_grid = BB / NB;                // 16

    // layer 0
    gemm_pre_k<<<gemm_grid, 256, 0, stream>>>(x, wih0, bih0, bhh0, pre, 128);
    lstm_rec_mfma<<<rec_grid, 256, 0, stream>>>(pre, whh0, hbuf, nullptr, nullptr, nullptr, 0);
    // layer 1
    gemm_pre_k<<<gemm_grid, 256, 0, stream>>>(hbuf, wih1, bih1, bhh1, pre, 64);
    lstm_rec_mfma<<<rec_grid, 256, 0, stream>>>(pre, whh1, hbuf, nullptr, nullptr, nullptr, 1);
    // layer 2 with fused FC
    gemm_pre_k<<<gemm_grid, 256, 0, stream>>>(hbuf, whh2 ? wih2 : wih2, bih2, bhh2, pre, 64);
    lstm_rec_mfma<<<rec_grid, 256, 0, stream>>>(pre, whh2, nullptr, outp, fcw, fcb, 2);
}